// Round 6
// baseline (167.551 us; speedup 1.0000x reference)
//
#include <hip/hip_runtime.h>
#include <hip/hip_bf16.h>
#include <math.h>

#define D_DIM 512
#define TILE  128

typedef float f32x4 __attribute__((ext_vector_type(4)));
typedef unsigned long long u64;

// ---- helpers ---------------------------------------------------------------

__device__ inline unsigned int fkey(float f) {
    unsigned int u = __float_as_uint(f);
    return (u & 0x80000000u) ? ~u : (u | 0x80000000u);
}

__device__ inline u64 shfl_xor_u64(u64 x, int m) {
    int lo = __shfl_xor((int)(unsigned)(x & 0xFFFFFFFFull), m, 64);
    int hi = __shfl_xor((int)(unsigned)(x >> 32), m, 64);
    return ((u64)(unsigned)hi << 32) | (u64)(unsigned)lo;
}

__device__ inline void async16(unsigned char* lds, const unsigned char* g) {
    __builtin_amdgcn_global_load_lds(
        (const __attribute__((address_space(1))) void*)g,
        (__attribute__((address_space(3))) void*)lds,
        16, 0, 0);
}

// ---- kernel 1: row L2-normalize -> fp8 e4m3 (x8 scale), init best ----------

__global__ __launch_bounds__(256) void normalize_rows(
        const float* __restrict__ in, unsigned char* __restrict__ xb,
        float* __restrict__ inv_norm, u64* __restrict__ best) {
    const int row  = blockIdx.x * 4 + (threadIdx.x >> 6);
    const int lane = threadIdx.x & 63;
    const float4* rp = (const float4*)(in + (size_t)row * D_DIM) + lane * 2;
    float4 a = rp[0], b = rp[1];
    float s = a.x*a.x + a.y*a.y + a.z*a.z + a.w*a.w
            + b.x*b.x + b.y*b.y + b.z*b.z + b.w*b.w;
    #pragma unroll
    for (int m = 1; m <= 32; m <<= 1) s += __shfl_xor(s, m, 64);
    float inv = 1.0f / fmaxf(sqrtf(s), 1e-8f);
    if (lane == 0) {
        inv_norm[row] = inv;
        best[row] = 0ull;   // below any real packed key
    }
    float sc = inv * 8.0f;  // x8: dots scale by 64 (monotone), dodges subnormals
    int lo = __builtin_amdgcn_cvt_pk_fp8_f32(a.x*sc, a.y*sc, 0, false);
    lo     = __builtin_amdgcn_cvt_pk_fp8_f32(a.z*sc, a.w*sc, lo, true);
    int hi = __builtin_amdgcn_cvt_pk_fp8_f32(b.x*sc, b.y*sc, 0, false);
    hi     = __builtin_amdgcn_cvt_pk_fp8_f32(b.z*sc, b.w*sc, hi, true);
    ((int2*)(xb + (size_t)row * D_DIM))[lane] = make_int2(lo, hi);
}

// ---- kernel 2: triangular C = X·Xᵀ, WHOLE-K LDS panels, fp8 MFMA -----------
// Both 128-row fp8 panels (64 KB each, D=512) fit in LDS: stage once, ONE
// barrier, then 256 barrier-free MFMAs/wave over full K — removes the 16
// vmcnt(0)+barrier drains/tile that capped R3 at 70 µs (1 block/CU is fine:
// drain ~1000 cyc vs 4136 cyc of MFMA). Padded-triangular schedule keeps
// bi%8 == blockIdx%8 -> per-XCD L2 A-band (R3-verified FETCH fix).
// Swizzle: LDS 16B-chunk p of row r holds global chunk p^(r&15); fragment
// b64 reads hit all 32 banks uniformly (data-volume minimum).

__global__ __launch_bounds__(256) void gemm_argmax(
        const unsigned char* __restrict__ X, u64* __restrict__ best) {
    __shared__ unsigned char As[TILE * D_DIM];   // 64 KB
    __shared__ unsigned char Bs[TILE * D_DIM];   // 64 KB
    __shared__ u64 rmerge[TILE * 2];
    __shared__ u64 cmerge[TILE * 2];

    // decode padded-triangular block id: group g = bj>>3, col width 8(g+1)
    int l = blockIdx.x;
    int g = (int)((sqrtf((float)l * 0.125f + 0.25f) - 0.5f) * 0.5f);
    while (32 * (g + 1) * (g + 2) <= l) ++g;
    while (32 * g * (g + 1) > l) --g;
    int rrem = l - 32 * g * (g + 1);
    int cw   = 8 * (g + 1);
    int c    = rrem / cw;
    int bi   = rrem - c * cw;
    int bj   = 8 * g + c;
    if (bi > bj) return;                 // padding block
    const int m0 = bi * TILE;
    const int n0 = bj * TILE;
    const bool offdiag = (bi != bj);

    const int t    = threadIdx.x;
    const int lane = t & 63;
    const int w    = t >> 6;
    const int wm   = w >> 1, wn = w & 1;
    const int qr   = lane & 15;
    const int quad = lane >> 4;

    // ---- stage both whole-K panels, one barrier ---------------------------
    const unsigned char* xA = X + (size_t)m0 * D_DIM;
    const unsigned char* xB = X + (size_t)n0 * D_DIM;
    #pragma unroll
    for (int j = 0; j < 16; j++) {
        int r    = j * 8 + (t >> 5);
        int srcc = ((t & 31) ^ ((j & 1) * 8 + (t >> 5))) * 16;
        const unsigned char* sA = xA + (size_t)r * D_DIM + srcc;
        const unsigned char* sB = xB + (size_t)r * D_DIM + srcc;
        async16(As + j * 4096 + t * 16, sA);
        async16(Bs + j * 4096 + t * 16, sB);
    }
    __syncthreads();   // single drain for the whole tile

    f32x4 acc[4][4];
    #pragma unroll
    for (int mi = 0; mi < 4; mi++)
        #pragma unroll
        for (int ni = 0; ni < 4; ni++)
            acc[mi][ni] = (f32x4){0.f, 0.f, 0.f, 0.f};

    // ---- barrier-free MFMA over full K ------------------------------------
    const int rowA = wm * 64 + qr;     // + mi*16
    const int rowB = wn * 64 + qr;     // + ni*16
    const int half = (quad & 1) * 8;
    #pragma unroll
    for (int ks = 0; ks < 16; ks++) {
        const int c0 = ks * 2 + (quad >> 1);
        long av[4], bv[4];
        #pragma unroll
        for (int mi = 0; mi < 4; mi++) {
            int row = rowA + mi * 16;
            int p   = c0 ^ qr;         // row&15 == qr
            av[mi] = *(const long*)(As + row * D_DIM + p * 16 + half);
        }
        #pragma unroll
        for (int ni = 0; ni < 4; ni++) {
            int row = rowB + ni * 16;
            int p   = c0 ^ qr;
            bv[ni] = *(const long*)(Bs + row * D_DIM + p * 16 + half);
        }
        #pragma unroll
        for (int mi = 0; mi < 4; mi++)
            #pragma unroll
            for (int ni = 0; ni < 4; ni++)
                acc[mi][ni] = __builtin_amdgcn_mfma_f32_16x16x32_fp8_fp8(
                    av[mi], bv[ni], acc[mi][ni], 0, 0, 0);
    }

    // ---- row-side argmax over this tile's 128 cols (diag masked) ----------
    const int colg_base = n0 + wn * 64 + qr;
    #pragma unroll
    for (int mi = 0; mi < 4; mi++) {
        #pragma unroll
        for (int r = 0; r < 4; r++) {
            const int rowl = wm * 64 + mi * 16 + quad * 4 + r;
            const int rowg = m0 + rowl;
            u64 key = 0ull;
            #pragma unroll
            for (int ni = 0; ni < 4; ni++) {
                int colg = colg_base + ni * 16;
                if (colg == rowg) continue;
                float v = acc[mi][ni][r];
                u64 k = ((u64)fkey(v) << 32) | (u64)(0xFFFFFFFFu - (unsigned)colg);
                key = key > k ? key : k;
            }
            #pragma unroll
            for (int m = 1; m <= 8; m <<= 1) {
                u64 o = shfl_xor_u64(key, m);
                key = key > o ? key : o;
            }
            if (qr == 0) rmerge[rowl * 2 + wn] = key;
        }
    }

    // ---- col-side argmax (symmetry) ---------------------------------------
    if (offdiag) {
        #pragma unroll
        for (int ni = 0; ni < 4; ni++) {
            u64 key = 0ull;
            #pragma unroll
            for (int mi = 0; mi < 4; mi++) {
                #pragma unroll
                for (int r = 0; r < 4; r++) {
                    int rowg = m0 + wm * 64 + mi * 16 + quad * 4 + r;
                    float v = acc[mi][ni][r];
                    u64 k = ((u64)fkey(v) << 32) | (u64)(0xFFFFFFFFu - (unsigned)rowg);
                    key = key > k ? key : k;
                }
            }
            u64 o = shfl_xor_u64(key, 16); key = key > o ? key : o;
            o     = shfl_xor_u64(key, 32); key = key > o ? key : o;
            if (quad == 0) cmerge[(wn * 64 + ni * 16 + qr) * 2 + wm] = key;
        }
    }
    __syncthreads();
    if (t < TILE) {
        u64 a = rmerge[t * 2], b = rmerge[t * 2 + 1];
        u64 k = a > b ? a : b;
        atomicMax(&best[m0 + t], k);
        if (offdiag) {
            u64 ca = cmerge[t * 2], cb = cmerge[t * 2 + 1];
            u64 ck = ca > cb ? ca : cb;
            atomicMax(&best[n0 + t], ck);
        }
    }
}

// ---- kernel 3: exact fp32 distance to chosen neighbor (1 wave/row) ---------

__global__ __launch_bounds__(256) void neighbor_dist(
        const float* __restrict__ in, const float* __restrict__ inv_norm,
        const u64* __restrict__ best, float* __restrict__ rowval) {
    const int row  = blockIdx.x * 4 + (threadIdx.x >> 6);
    const int lane = threadIdx.x & 63;
    u64 k   = best[row];
    int nbr = (int)(0xFFFFFFFFu - (unsigned)(k & 0xFFFFFFFFull));
    float ir  = inv_norm[row];
    float inb = inv_norm[nbr];
    const float4* rp = (const float4*)(in + (size_t)row * D_DIM) + lane * 2;
    const float4* np = (const float4*)(in + (size_t)nbr * D_DIM) + lane * 2;
    float4 r0 = rp[0], r1 = rp[1], n0 = np[0], n1 = np[1];
    float d0 = r0.x*ir - n0.x*inb + 1e-8f, d1 = r0.y*ir - n0.y*inb + 1e-8f;
    float d2 = r0.z*ir - n0.z*inb + 1e-8f, d3 = r0.w*ir - n0.w*inb + 1e-8f;
    float d4 = r1.x*ir - n1.x*inb + 1e-8f, d5 = r1.y*ir - n1.y*inb + 1e-8f;
    float d6 = r1.z*ir - n1.z*inb + 1e-8f, d7 = r1.w*ir - n1.w*inb + 1e-8f;
    float s = d0*d0 + d1*d1 + d2*d2 + d3*d3 + d4*d4 + d5*d5 + d6*d6 + d7*d7;
    #pragma unroll
    for (int m = 1; m <= 32; m <<= 1) s += __shfl_xor(s, m, 64);
    if (lane == 0) rowval[row] = logf(sqrtf(s) + 1e-8f);
}

// ---- kernel 4: final mean --------------------------------------------------

__global__ __launch_bounds__(256) void final_reduce(
        const float* __restrict__ rowval, float* __restrict__ out, int B) {
    int t = threadIdx.x;
    const float4* rv = (const float4*)rowval;
    float s = 0.f;
    for (int i = t; i < B / 4; i += 256) {
        float4 v = rv[i];
        s += v.x + v.y + v.z + v.w;
    }
    #pragma unroll
    for (int m = 1; m <= 32; m <<= 1) s += __shfl_xor(s, m, 64);
    __shared__ float sb[4];
    if ((t & 63) == 0) sb[t >> 6] = s;
    __syncthreads();
    if (t == 0) out[0] = -(sb[0] + sb[1] + sb[2] + sb[3]) / (float)B;
}

// ---- launch ----------------------------------------------------------------

extern "C" void kernel_launch(void* const* d_in, const int* in_sizes, int n_in,
                              void* d_out, int out_size, void* d_ws, size_t ws_size,
                              hipStream_t stream) {
    const float* in = (const float*)d_in[0];
    const int B  = in_sizes[0] / D_DIM;         // 8192
    const int nt = B / TILE;                    // 64
    const int ng = nt / 8;                      // 8
    const int nblk = 32 * ng * (ng + 1);        // 2304 padded-triangular blocks

    char* w = (char*)d_ws;
    unsigned char* xb = (unsigned char*)w;                     // B*D fp8
    float*  invn   = (float*)(w + (size_t)B * D_DIM);
    u64*    best   = (u64*)(w + (size_t)B * D_DIM + (size_t)B * 4);
    float*  rowval = (float*)(w + (size_t)B * D_DIM + (size_t)B * 4 + (size_t)B * 8);
    float*  out    = (float*)d_out;

    normalize_rows<<<B / 4, 256, 0, stream>>>(in, xb, invn, best);
    gemm_argmax<<<nblk, 256, 0, stream>>>(xb, best);
    neighbor_dist<<<B / 4, 256, 0, stream>>>(in, invn, best, rowval);
    final_reduce<<<1, 256, 0, stream>>>(rowval, out, B);
}

// Round 7
// 140.272 us; speedup vs baseline: 1.1945x; 1.1945x over previous
//
#include <hip/hip_runtime.h>
#include <hip/hip_bf16.h>
#include <math.h>

#define D_DIM 512
#define TILE  128
#define BK    64

typedef float f32x4 __attribute__((ext_vector_type(4)));
typedef unsigned long long u64;

// ---- helpers ---------------------------------------------------------------

__device__ inline unsigned int fkey(float f) {
    unsigned int u = __float_as_uint(f);
    return (u & 0x80000000u) ? ~u : (u | 0x80000000u);
}

__device__ inline u64 shfl_xor_u64(u64 x, int m) {
    int lo = __shfl_xor((int)(unsigned)(x & 0xFFFFFFFFull), m, 64);
    int hi = __shfl_xor((int)(unsigned)(x >> 32), m, 64);
    return ((u64)(unsigned)hi << 32) | (u64)(unsigned)lo;
}

__device__ inline void async16(unsigned char* lds, const unsigned char* g) {
    __builtin_amdgcn_global_load_lds(
        (const __attribute__((address_space(1))) void*)g,
        (__attribute__((address_space(3))) void*)lds,
        16, 0, 0);
}

// ---- kernel 1: row L2-normalize -> fp8 e4m3 (x8 scale), init best/acc/cnt --

__global__ __launch_bounds__(256) void normalize_rows(
        const float* __restrict__ in, unsigned char* __restrict__ xb,
        float* __restrict__ inv_norm, u64* __restrict__ best,
        float* __restrict__ acc, int* __restrict__ cnt) {
    const int row  = blockIdx.x * 4 + (threadIdx.x >> 6);
    const int lane = threadIdx.x & 63;
    if (blockIdx.x == 0 && threadIdx.x == 0) { acc[0] = 0.f; cnt[0] = 0; }
    const float4* rp = (const float4*)(in + (size_t)row * D_DIM) + lane * 2;
    float4 a = rp[0], b = rp[1];
    float s = a.x*a.x + a.y*a.y + a.z*a.z + a.w*a.w
            + b.x*b.x + b.y*b.y + b.z*b.z + b.w*b.w;
    #pragma unroll
    for (int m = 1; m <= 32; m <<= 1) s += __shfl_xor(s, m, 64);
    float inv = 1.0f / fmaxf(sqrtf(s), 1e-8f);
    if (lane == 0) {
        inv_norm[row] = inv;
        best[row] = 0ull;   // below any real packed key
    }
    float sc = inv * 8.0f;  // x8: dots scale by 64 (monotone), dodges subnormals
    int lo = __builtin_amdgcn_cvt_pk_fp8_f32(a.x*sc, a.y*sc, 0, false);
    lo     = __builtin_amdgcn_cvt_pk_fp8_f32(a.z*sc, a.w*sc, lo, true);
    int hi = __builtin_amdgcn_cvt_pk_fp8_f32(b.x*sc, b.y*sc, 0, false);
    hi     = __builtin_amdgcn_cvt_pk_fp8_f32(b.z*sc, b.w*sc, hi, true);
    ((int2*)(xb + (size_t)row * D_DIM))[lane] = make_int2(lo, hi);
}

// ---- kernel 2: triangular C = X·Xᵀ (fp8 MFMA), double-buffered LDS ---------
// R3 core (best measured gemm: 70.5 us) + ping-pong LDS staging: next k0's
// global_load_lds issues BEFORE computing the current buffer, so the L2->LDS
// staging (~273 cyc/iter) overlaps MFMA instead of serializing; barriers
// drop 16 -> 9 per tile. Padded-triangular schedule keeps bi%8 == blockIdx%8
// -> per-XCD L2 A-band residency (R3-verified FETCH fix).

__global__ __launch_bounds__(256) void gemm_argmax(
        const unsigned char* __restrict__ X, u64* __restrict__ best) {
    __shared__ unsigned char As[2][TILE * BK];   // 2 x 8 KB
    __shared__ unsigned char Bs[2][TILE * BK];   // 2 x 8 KB
    __shared__ u64 rmerge[TILE * 2];
    __shared__ u64 cmerge[TILE * 2];

    // decode padded-triangular block id: group g = bj>>3, col width 8(g+1)
    int l = blockIdx.x;
    int g = (int)((sqrtf((float)l * 0.125f + 0.25f) - 0.5f) * 0.5f);
    while (32 * (g + 1) * (g + 2) <= l) ++g;
    while (32 * g * (g + 1) > l) --g;
    int rrem = l - 32 * g * (g + 1);
    int cw   = 8 * (g + 1);
    int c    = rrem / cw;
    int bi   = rrem - c * cw;
    int bj   = 8 * g + c;
    if (bi > bj) return;                 // padding block
    const int m0 = bi * TILE;
    const int n0 = bj * TILE;
    const bool offdiag = (bi != bj);

    const int t    = threadIdx.x;
    const int lane = t & 63;
    const int w    = t >> 6;
    const int wm   = w >> 1, wn = w & 1;
    const int qr   = lane & 15;
    const int quad = lane >> 4;

    // staging: thread t -> row t>>2, LDS 16B-granule t&3, source granule
    // (t&3)^((row>>1)&3)  [global_load_lds-compatible swizzle, R3-verified]
    const int rS   = t >> 2;
    const int gSrc = ((t & 3) ^ ((t >> 3) & 3)) * 16;
    const unsigned char* gA = X + (size_t)(m0 + rS) * D_DIM + gSrc;
    const unsigned char* gB = X + (size_t)(n0 + rS) * D_DIM + gSrc;

    f32x4 acc[4][4];
    #pragma unroll
    for (int mi = 0; mi < 4; mi++)
        #pragma unroll
        for (int ni = 0; ni < 4; ni++)
            acc[mi][ni] = (f32x4){0.f, 0.f, 0.f, 0.f};

    // prologue: stage k0=0 into buffer 0
    async16(&As[0][t * 16],           gA);
    async16(&As[0][64 * BK + t * 16], gA + (size_t)64 * D_DIM);
    async16(&Bs[0][t * 16],           gB);
    async16(&Bs[0][64 * BK + t * 16], gB + (size_t)64 * D_DIM);
    __syncthreads();

    const int NIT = D_DIM / BK;          // 8
    for (int it = 0; it < NIT; it++) {
        const int cur = it & 1;
        if (it + 1 < NIT) {
            const int nxt = cur ^ 1;
            const int kn  = (it + 1) * BK;
            async16(&As[nxt][t * 16],           gA + kn);
            async16(&As[nxt][64 * BK + t * 16], gA + (size_t)64 * D_DIM + kn);
            async16(&Bs[nxt][t * 16],           gB + kn);
            async16(&Bs[nxt][64 * BK + t * 16], gB + (size_t)64 * D_DIM + kn);
        }
        const unsigned char* Ab = As[cur];
        const unsigned char* Bb = Bs[cur];
        #pragma unroll
        for (int ks = 0; ks < 2; ks++) {
            long av[4], bv[4];
            #pragma unroll
            for (int mi = 0; mi < 4; mi++) {
                int row = wm * 64 + mi * 16 + qr;
                int cl  = (ks * 4 + quad) ^ (qr & 6);
                av[mi] = *(const long*)(Ab + row * BK + cl * 8);
            }
            #pragma unroll
            for (int ni = 0; ni < 4; ni++) {
                int row = wn * 64 + ni * 16 + qr;
                int cl  = (ks * 4 + quad) ^ (qr & 6);
                bv[ni] = *(const long*)(Bb + row * BK + cl * 8);
            }
            #pragma unroll
            for (int mi = 0; mi < 4; mi++)
                #pragma unroll
                for (int ni = 0; ni < 4; ni++)
                    acc[mi][ni] = __builtin_amdgcn_mfma_f32_16x16x32_fp8_fp8(
                        av[mi], bv[ni], acc[mi][ni], 0, 0, 0);
        }
        __syncthreads();   // drains prefetch (ran during MFMA) + fences reuse
    }

    // ---- row-side argmax over this tile's 128 cols (diag masked) ----------
    const int colg_base = n0 + wn * 64 + qr;
    #pragma unroll
    for (int mi = 0; mi < 4; mi++) {
        #pragma unroll
        for (int r = 0; r < 4; r++) {
            const int rowl = wm * 64 + mi * 16 + quad * 4 + r;
            const int rowg = m0 + rowl;
            u64 key = 0ull;
            #pragma unroll
            for (int ni = 0; ni < 4; ni++) {
                int colg = colg_base + ni * 16;
                if (colg == rowg) continue;
                float v = acc[mi][ni][r];
                u64 k = ((u64)fkey(v) << 32) | (u64)(0xFFFFFFFFu - (unsigned)colg);
                key = key > k ? key : k;
            }
            #pragma unroll
            for (int m = 1; m <= 8; m <<= 1) {
                u64 o = shfl_xor_u64(key, m);
                key = key > o ? key : o;
            }
            if (qr == 0) rmerge[rowl * 2 + wn] = key;
        }
    }

    // ---- col-side argmax (symmetry) ---------------------------------------
    if (offdiag) {
        #pragma unroll
        for (int ni = 0; ni < 4; ni++) {
            u64 key = 0ull;
            #pragma unroll
            for (int mi = 0; mi < 4; mi++) {
                #pragma unroll
                for (int r = 0; r < 4; r++) {
                    int rowg = m0 + wm * 64 + mi * 16 + quad * 4 + r;
                    float v = acc[mi][ni][r];
                    u64 k = ((u64)fkey(v) << 32) | (u64)(0xFFFFFFFFu - (unsigned)rowg);
                    key = key > k ? key : k;
                }
            }
            u64 o = shfl_xor_u64(key, 16); key = key > o ? key : o;
            o     = shfl_xor_u64(key, 32); key = key > o ? key : o;
            if (quad == 0) cmerge[(wn * 64 + ni * 16 + qr) * 2 + wm] = key;
        }
    }
    __syncthreads();
    if (t < TILE) {
        u64 a = rmerge[t * 2], b = rmerge[t * 2 + 1];
        u64 k = a > b ? a : b;
        atomicMax(&best[m0 + t], k);
        if (offdiag) {
            u64 ca = cmerge[t * 2], cb = cmerge[t * 2 + 1];
            u64 ck = ca > cb ? ca : cb;
            atomicMax(&best[n0 + t], ck);
        }
    }
}

// ---- kernel 3: exact fp32 distance + fused mean (256-block cheap ticket) ---

__global__ __launch_bounds__(256) void neighbor_reduce(
        const float* __restrict__ in, const float* __restrict__ inv_norm,
        const u64* __restrict__ best, float* __restrict__ acc,
        int* __restrict__ cnt, float* __restrict__ out, int B) {
    const int wave = threadIdx.x >> 6;
    const int lane = threadIdx.x & 63;
    float lsum = 0.f;
    #pragma unroll
    for (int rr = 0; rr < 8; rr++) {
        const int row = blockIdx.x * 32 + wave * 8 + rr;
        u64 k   = best[row];
        int nbr = (int)(0xFFFFFFFFu - (unsigned)(k & 0xFFFFFFFFull));
        float ir  = inv_norm[row];
        float inb = inv_norm[nbr];
        const float4* rp = (const float4*)(in + (size_t)row * D_DIM) + lane * 2;
        const float4* np = (const float4*)(in + (size_t)nbr * D_DIM) + lane * 2;
        float4 r0 = rp[0], r1 = rp[1], q0 = np[0], q1 = np[1];
        float d0 = r0.x*ir - q0.x*inb + 1e-8f, d1 = r0.y*ir - q0.y*inb + 1e-8f;
        float d2 = r0.z*ir - q0.z*inb + 1e-8f, d3 = r0.w*ir - q0.w*inb + 1e-8f;
        float d4 = r1.x*ir - q1.x*inb + 1e-8f, d5 = r1.y*ir - q1.y*inb + 1e-8f;
        float d6 = r1.z*ir - q1.z*inb + 1e-8f, d7 = r1.w*ir - q1.w*inb + 1e-8f;
        float s = d0*d0 + d1*d1 + d2*d2 + d3*d3 + d4*d4 + d5*d5 + d6*d6 + d7*d7;
        #pragma unroll
        for (int m = 1; m <= 32; m <<= 1) s += __shfl_xor(s, m, 64);
        if (lane == 0) lsum += logf(sqrtf(s) + 1e-8f);
    }
    __shared__ float sb[4];
    if (lane == 0) sb[wave] = lsum;
    __syncthreads();
    if (threadIdx.x == 0) {
        float partial = sb[0] + sb[1] + sb[2] + sb[3];
        atomicAdd(acc, partial);
        __threadfence();
        int done = atomicAdd(cnt, 1);
        if (done == gridDim.x - 1) {
            __threadfence();
            float tot = atomicAdd(acc, 0.0f);   // device-scope read of final sum
            out[0] = -tot / (float)B;
        }
    }
}

// ---- launch ----------------------------------------------------------------

extern "C" void kernel_launch(void* const* d_in, const int* in_sizes, int n_in,
                              void* d_out, int out_size, void* d_ws, size_t ws_size,
                              hipStream_t stream) {
    const float* in = (const float*)d_in[0];
    const int B  = in_sizes[0] / D_DIM;         // 8192
    const int nt = B / TILE;                    // 64
    const int ng = nt / 8;                      // 8
    const int nblk = 32 * ng * (ng + 1);        // 2304 padded-triangular blocks

    char* w = (char*)d_ws;
    unsigned char* xb = (unsigned char*)w;                     // B*D fp8
    float* invn = (float*)(w + (size_t)B * D_DIM);
    u64*   best = (u64*)(w + (size_t)B * D_DIM + (size_t)B * 4);
    float* acc  = (float*)(w + (size_t)B * D_DIM + (size_t)B * 4 + (size_t)B * 8);
    int*   cnt  = (int*)(acc + 1);
    float* out  = (float*)d_out;

    normalize_rows<<<B / 4, 256, 0, stream>>>(in, xb, invn, best, acc, cnt);
    gemm_argmax<<<nblk, 256, 0, stream>>>(xb, best);
    neighbor_reduce<<<B / 32, 256, 0, stream>>>(in, invn, best, acc, cnt, out, B);
}